// Round 7
// baseline (789.824 us; speedup 1.0000x reference)
//
#include <hip/hip_runtime.h>
#include <math.h>

#define TILE 128
#define BK   64
#define NT   256

typedef __attribute__((ext_vector_type(8))) short bf16x8;
typedef __attribute__((ext_vector_type(4))) float f32x4;

typedef const __attribute__((address_space(1))) void* gvp;
typedef __attribute__((address_space(3))) void* lvp;

__device__ __forceinline__ float bf2f(unsigned short u) {
  union { unsigned int i; float f; } v; v.i = ((unsigned int)u) << 16; return v.f;
}
__device__ __forceinline__ unsigned short f2bf(float f) {
  union { float ff; unsigned int i; } v; v.ff = f;
  return (unsigned short)((v.i + 0x7fffu + ((v.i >> 16) & 1u)) >> 16);
}

// bijective XCD-chunk swizzle (m204): hardware dispatches linear ids round-robin
// across 8 XCDs; remap so each XCD owns a contiguous logical chunk -> blocks
// sharing an input panel land on the same XCD's L2.
__device__ __forceinline__ int xcd_swz(int h, int nwg) {
  int q = nwg >> 3, r = nwg & 7;
  int xcd = h & 7, pos = h >> 3;
  return (xcd < r ? xcd * (q + 1) : r * (q + 1) + (xcd - r) * q) + pos;
}

struct GemmSrc { const unsigned short* A; int lda; const unsigned short* B; int ldb; int nk; };

// Stage a 128x64 bf16 tile (row-major, rows r0.., k offset k0) into LDS.
// 1024 16B chunks, 4 per thread; LDS dest linear: base + cid*16B
// (wave-uniform base + lane*16 as required by global_load_lds).
__device__ __forceinline__ void stage_tile(const unsigned short* g, int ld, int r0, int k0,
                                           short* lds, int tid) {
#pragma unroll
  for (int i = 0; i < 4; ++i) {
    int cid = i * NT + tid;
    int row = cid >> 3, kc = cid & 7;
    const unsigned short* src = g + (size_t)(r0 + row) * ld + (k0 + kc * 8);
    __builtin_amdgcn_global_load_lds((gvp)src, (lvp)(lds + cid * 8), 16, 0, 0);
  }
}

__device__ __forceinline__ void compute_tile(const short* As, const short* Bs,
                                             f32x4 acc[4][4], int lr, int lk, int wm, int wn) {
#pragma unroll
  for (int kk = 0; kk < 2; ++kk) {
    bf16x8 a[4], b[4];
#pragma unroll
    for (int i = 0; i < 4; ++i) {
      a[i] = *(const bf16x8*)(As + (wm * 64 + i * 16 + lr) * BK + kk * 32 + lk * 8);
      b[i] = *(const bf16x8*)(Bs + (wn * 64 + i * 16 + lr) * BK + kk * 32 + lk * 8);
    }
#pragma unroll
    for (int i = 0; i < 4; ++i)
#pragma unroll
      for (int j = 0; j < 4; ++j)
        acc[i][j] = __builtin_amdgcn_mfma_f32_16x16x32_bf16(a[i], b[j], acc[i][j], 0, 0, 0);
  }
}

// single-buffered K-loop (>=3 blocks/CU: implicit inter-wave overlap hides drain)
template<int NS>
__device__ __forceinline__ void gemm_accum(const GemmSrc* s, f32x4 acc[4][4],
                                           short* As, short* Bs, int tid, int r0, int c0) {
  int lane = tid & 63, w = tid >> 6;
  int lr = lane & 15, lk = lane >> 4;
  int wm = w >> 1, wn = w & 1;
#pragma unroll
  for (int si = 0; si < NS; ++si) {
    int nk = s[si].nk;
    for (int kt = 0; kt < nk; ++kt) {
      __syncthreads();                                   // prev compute done before overwrite
      stage_tile(s[si].A, s[si].lda, r0, kt * BK, As, tid);
      stage_tile(s[si].B, s[si].ldb, c0, kt * BK, Bs, tid);
      __syncthreads();                                   // drains vmcnt(0): staging visible
      compute_tile(As, Bs, acc, lr, lk, wm, wn);
    }
  }
}

// map flat K-step -> (source, local kt) and stage its A/B tiles
template<int NS>
__device__ __forceinline__ void stage_step(const GemmSrc* s, int step, short* A, short* B,
                                           int r0, int c0, int tid) {
  int si = 0, t = step;
#pragma unroll
  for (int i = 0; i < NS - 1; ++i) { if (t >= s[i].nk) { t -= s[i].nk; si = i + 1; } }
  stage_tile(s[si].A, s[si].lda, r0, t * BK, A, tid);
  stage_tile(s[si].B, s[si].ldb, c0, t * BK, B, tid);
}

// double-buffered K-loop (fallback path for the non-split config)
template<int NS>
__device__ __forceinline__ void gemm_accum_dbuf(const GemmSrc* s, f32x4 acc[4][4],
                                                short* As0, short* Bs0, short* As1, short* Bs1,
                                                int tid, int r0, int c0) {
  int lane = tid & 63, w = tid >> 6;
  int lr = lane & 15, lk = lane >> 4;
  int wm = w >> 1, wn = w & 1;
  int total = 0;
#pragma unroll
  for (int si = 0; si < NS; ++si) total += s[si].nk;
  stage_step<NS>(s, 0, As0, Bs0, r0, c0, tid);
  __syncthreads();
  for (int step = 0; step < total; ++step) {
    short* Ac = (step & 1) ? As1 : As0;
    short* Bc = (step & 1) ? Bs1 : Bs0;
    short* An = (step & 1) ? As0 : As1;
    short* Bn = (step & 1) ? Bs0 : Bs1;
    if (step + 1 < total) stage_step<NS>(s, step + 1, An, Bn, r0, c0, tid);
    compute_tile(Ac, Bc, acc, lr, lk, wm, wn);
    __syncthreads();
  }
}

// C/D layout for mfma_f32_16x16x32_bf16: col = lane&15, row = (lane>>4)*4 + reg
template<bool OUT_BF16, bool BIAS_N, bool BIAS_M>
__device__ __forceinline__ void gemm_epilogue(f32x4 acc[4][4], void* C, int ldc,
                                              int r0, int c0, const float* bias,
                                              float alpha, int tid) {
  int lane = tid & 63, w = tid >> 6;
  int lr = lane & 15, lk = lane >> 4;
  int wm = w >> 1, wn = w & 1;
#pragma unroll
  for (int i = 0; i < 4; ++i) {
#pragma unroll
    for (int j = 0; j < 4; ++j) {
      int col = c0 + wn * 64 + j * 16 + lr;
      float bn = BIAS_N ? bias[col] : 0.f;
#pragma unroll
      for (int r = 0; r < 4; ++r) {
        int row = r0 + wm * 64 + i * 16 + lk * 4 + r;
        float v = acc[i][j][r] * alpha + bn;
        if (BIAS_M) v += bias[row];
        size_t idx = (size_t)row * ldc + col;
        if (OUT_BF16) ((unsigned short*)C)[idx] = f2bf(v);
        else          ((float*)C)[idx] = v;
      }
    }
  }
}

// split-K epilogue: f32 atomic accumulate (exactly KSPLIT adds per element)
__device__ __forceinline__ void gemm_epilogue_atomic(f32x4 acc[4][4], float* C, int ldc,
                                                     int r0, int c0, int tid) {
  int lane = tid & 63, w = tid >> 6;
  int lr = lane & 15, lk = lane >> 4;
  int wm = w >> 1, wn = w & 1;
#pragma unroll
  for (int i = 0; i < 4; ++i)
#pragma unroll
    for (int j = 0; j < 4; ++j) {
      int col = c0 + wn * 64 + j * 16 + lr;
#pragma unroll
      for (int r = 0; r < 4; ++r) {
        int row = r0 + wm * 64 + i * 16 + lk * 4 + r;
        atomicAdd(&C[(size_t)row * ldc + col], acc[i][j][r]);
      }
    }
}

__device__ __forceinline__ void zero_acc(f32x4 acc[4][4]) {
  f32x4 z = { 0.f, 0.f, 0.f, 0.f };
#pragma unroll
  for (int i = 0; i < 4; ++i)
#pragma unroll
    for (int j = 0; j < 4; ++j) acc[i][j] = z;
}

// ---------------- kernels ----------------

struct ConvW { const float* src[7]; unsigned short* dst[7]; };

__global__ __launch_bounds__(NT) void k_convert_w(ConvW a) {
  int z = blockIdx.y;
  const float* s = a.src[z];
  unsigned short* d = a.dst[z];
  const int n = 768 * 768;
  int stride = gridDim.x * NT * 4;
  for (int i = ((int)blockIdx.x * NT + (int)threadIdx.x) * 4; i < n; i += stride) {
    float4 f = *(const float4*)(s + i);
    ushort4 o;
    o.x = f2bf(f.x); o.y = f2bf(f.y); o.z = f2bf(f.z); o.w = f2bf(f.w);
    *(ushort4*)(d + i) = o;
  }
}

__global__ __launch_bounds__(NT) void k_convert_z(const float* zg, const float* zl,
                                                  unsigned short* dg, unsigned short* dl,
                                                  long long off, int n) {
  const float* s = (blockIdx.y ? zl : zg) + off;
  unsigned short* d = blockIdx.y ? dl : dg;
  int stride = gridDim.x * NT * 4;
  for (int i = ((int)blockIdx.x * NT + (int)threadIdx.x) * 4; i < n; i += stride) {
    float4 f = *(const float4*)(s + i);
    ushort4 o;
    o.x = f2bf(f.x); o.y = f2bf(f.y); o.z = f2bf(f.z); o.w = f2bf(f.w);
    *(ushort4*)(d + i) = o;
  }
}

__global__ __launch_bounds__(NT) void k_zero(float* p, int n4) {
  int i = ((int)blockIdx.x * NT + (int)threadIdx.x) * 4;
  if (i < n4 * 4) *(float4*)(p + i) = make_float4(0.f, 0.f, 0.f, 0.f);
}

__global__ __launch_bounds__(NT) void k_zf(const float* src, unsigned short* dst, int n) {
  int i = ((int)blockIdx.x * NT + (int)threadIdx.x) * 4;
  if (i < n) {
    float4 f = *(const float4*)(src + i);
    ushort4 o;
    o.x = f2bf(f.x); o.y = f2bf(f.y); o.z = f2bf(f.z); o.w = f2bf(f.w);
    *(ushort4*)(dst + i) = o;
  }
}

struct ProjArgs {
  const unsigned short* src[4];
  const unsigned short* W[4];
  const float* bias[4];
  unsigned short* dst[4];
};

// dst = src @ W^T + b : M=SG, N=768, K=768 (group-local rows)
__global__ __launch_bounds__(NT) void k_proj(ProjArgs p) {
  __shared__ __align__(16) short As[TILE * BK], Bs[TILE * BK];
  int z = blockIdx.z;
  int r0 = blockIdx.y * TILE, c0 = blockIdx.x * TILE;
  f32x4 acc[4][4]; zero_acc(acc);
  GemmSrc s = { p.src[z], 768, p.W[z], 768, 768 / BK };
  gemm_accum<1>(&s, acc, As, Bs, threadIdx.x, r0, c0);
  gemm_epilogue<true, true, false>(acc, p.dst[z], 768, r0, c0, p.bias[z], 1.f, threadIdx.x);
}

struct ProjVTArgs {
  const unsigned short* Wv[2];
  const unsigned short* Z[2];
  const float* bias[2];
  unsigned short* dst[2];
  int ldc;  // = SG
};

// V^T = Wv @ Z_grp^T (+ bias per ROW e) : M=768, N=SG, K=768, C is [768][SG]
__global__ __launch_bounds__(NT) void k_projvt(ProjVTArgs p) {
  __shared__ __align__(16) short As[TILE * BK], Bs[TILE * BK];
  int z = blockIdx.z;
  int r0 = blockIdx.y * TILE, c0 = blockIdx.x * TILE;
  f32x4 acc[4][4]; zero_acc(acc);
  GemmSrc s = { p.Wv[z], 768, p.Z[z], 768, 768 / BK };
  gemm_accum<1>(&s, acc, As, Bs, threadIdx.x, r0, c0);
  gemm_epilogue<true, false, true>(acc, p.dst[z], p.ldc, r0, c0, p.bias[z], 1.f, threadIdx.x);
}

// S[z] = Q_gi @ K_gi^T * alpha, group-local: z in [0,2G). XCD-swizzled.
__global__ __launch_bounds__(NT) void k_scores(const unsigned short* Qg, const unsigned short* Kl,
                                               const unsigned short* Ql, const unsigned short* Kg,
                                               unsigned short* S, float alpha, int G) {
  __shared__ __align__(16) short As[TILE * BK], Bs[TILE * BK];
  int nwg = (int)(gridDim.x * gridDim.y * gridDim.z);
  int h = (int)blockIdx.x + (int)gridDim.x * ((int)blockIdx.y + (int)gridDim.y * (int)blockIdx.z);
  int l = xcd_swz(h, nwg);
  int x = l & 15, y = (l >> 4) & 15, z = l >> 8;
  int dir = (z >= G) ? 1 : 0, gi = z - dir * G;
  const unsigned short* Q = (dir ? Ql : Qg) + (size_t)gi * 2048 * 768;
  const unsigned short* K = (dir ? Kg : Kl) + (size_t)gi * 2048 * 768;
  unsigned short* C = S + (size_t)z * 2048 * 2048;
  int r0 = y * TILE, c0 = x * TILE;
  f32x4 acc[4][4]; zero_acc(acc);
  GemmSrc s = { Q, 768, K, 768, 768 / BK };
  gemm_accum<1>(&s, acc, As, Bs, threadIdx.x, r0, c0);
  gemm_epilogue<true, false, false>(acc, C, 2048, r0, c0, nullptr, alpha, threadIdx.x);
}

// in-place row softmax over 2048 bf16, one block per row
__global__ __launch_bounds__(NT) void k_softmax(unsigned short* S) {
  __shared__ float red[8];
  unsigned short* p = S + (size_t)blockIdx.x * 2048;
  int t = threadIdx.x, lane = t & 63, w = t >> 6;
  union { uint4 q; unsigned short u[8]; } raw;
  raw.q = ((const uint4*)p)[t];
  float v[8]; float mx = -3.0e38f;
#pragma unroll
  for (int i = 0; i < 8; ++i) { v[i] = bf2f(raw.u[i]); mx = fmaxf(mx, v[i]); }
#pragma unroll
  for (int off = 32; off > 0; off >>= 1) mx = fmaxf(mx, __shfl_xor(mx, off));
  if (lane == 0) red[w] = mx;
  __syncthreads();
  mx = fmaxf(fmaxf(red[0], red[1]), fmaxf(red[2], red[3]));
  float sum = 0.f;
#pragma unroll
  for (int i = 0; i < 8; ++i) { v[i] = __expf(v[i] - mx); sum += v[i]; }
#pragma unroll
  for (int off = 32; off > 0; off >>= 1) sum += __shfl_xor(sum, off);
  if (lane == 0) red[4 + w] = sum;
  __syncthreads();
  sum = (red[4] + red[5]) + (red[6] + red[7]);
  float inv = 1.f / sum;
#pragma unroll
  for (int i = 0; i < 8; ++i) raw.u[i] = f2bf(v[i] * inv);
  ((uint4*)p)[t] = raw.q;
}

// split-K PV: Zacc[gi] += P_src(half) @ V_src(half). z encodes (half,src,gi):
// gi = z%G, src = (z/G)%2, half = z/(2G). Each block: 16 K-tiles of one
// source-half, f32 atomicAdd epilogue. Grid 6*16*4G blocks, XCD-swizzled.
__global__ __launch_bounds__(NT) void k_pv_sk(const unsigned short* S, const unsigned short* VlT,
                                              const unsigned short* VgT, float* Zacc,
                                              int G, int SG) {
  __shared__ __align__(16) short As[TILE * BK], Bs[TILE * BK];
  int nwg = (int)(gridDim.x * gridDim.y * gridDim.z);
  int h = (int)blockIdx.x + (int)gridDim.x * ((int)blockIdx.y + (int)gridDim.y * (int)blockIdx.z);
  int l = xcd_swz(h, nwg);
  int x = l % 6, t2 = l / 6;
  int y = t2 & 15, z = t2 >> 4;          // z in [0, 4G)
  int gi = z % G, src = (z / G) & 1, half = z / (2 * G);
  const unsigned short* Sl = S + (size_t)(src * G + gi) * 2048 * 2048;
  const unsigned short* V = src ? VgT : VlT;
  int r0 = y * TILE, c0 = x * TILE;
  int lane = threadIdx.x & 63, wv = threadIdx.x >> 6;
  int lr = lane & 15, lk = lane >> 4, wm = wv >> 1, wn = wv & 1;
  f32x4 acc[4][4]; zero_acc(acc);
  for (int kt = 0; kt < 16; ++kt) {
    int k0 = (half * 16 + kt) * BK;
    __syncthreads();
    stage_tile(Sl, 2048, r0, k0, As, threadIdx.x);
    stage_tile(V, SG, c0, gi * 2048 + k0, Bs, threadIdx.x);
    __syncthreads();
    compute_tile(As, Bs, acc, lr, lk, wm, wn);
  }
  gemm_epilogue_atomic(acc, Zacc + (size_t)gi * 2048 * 768, 768, r0, c0, threadIdx.x);
}

// fallback (non-split) PV, double-buffered
__global__ __launch_bounds__(NT) void k_pv(const unsigned short* S, const unsigned short* VlT,
                                           const unsigned short* VgT, unsigned short* Zf,
                                           int G, int SG) {
  __shared__ __align__(16) short As0[TILE * BK], Bs0[TILE * BK];
  __shared__ __align__(16) short As1[TILE * BK], Bs1[TILE * BK];
  int z = blockIdx.z;
  int r0 = blockIdx.y * TILE, c0 = blockIdx.x * TILE;
  f32x4 acc[4][4]; zero_acc(acc);
  GemmSrc s[2] = {
    { S + (size_t)z * 2048 * 2048,       2048, VlT + (size_t)z * 2048, SG, 2048 / BK },
    { S + (size_t)(G + z) * 2048 * 2048, 2048, VgT + (size_t)z * 2048, SG, 2048 / BK }
  };
  gemm_accum_dbuf<2>(s, acc, As0, Bs0, As1, Bs1, threadIdx.x, r0, c0);
  gemm_epilogue<true, false, false>(acc, Zf + (size_t)z * 2048 * 768, 768, r0, c0,
                                    nullptr, 1.f, threadIdx.x);
}

// out_grp = Zf_grp @ Wf^T + bf (fp32 out) : M=SG, N=768, K=768
__global__ __launch_bounds__(NT) void k_final(const unsigned short* Zf, const unsigned short* Wf,
                                              const float* bias, float* out) {
  __shared__ __align__(16) short As[TILE * BK], Bs[TILE * BK];
  int r0 = blockIdx.y * TILE, c0 = blockIdx.x * TILE;
  f32x4 acc[4][4]; zero_acc(acc);
  GemmSrc s = { Zf, 768, Wf, 768, 768 / BK };
  gemm_accum<1>(&s, acc, As, Bs, threadIdx.x, r0, c0);
  gemm_epilogue<false, true, false>(acc, out, 768, r0, c0, bias, 1.f, threadIdx.x);
}

// ---------------- launch ----------------

extern "C" void kernel_launch(void* const* d_in, const int* in_sizes, int n_in,
                              void* d_out, int out_size, void* d_ws, size_t ws_size,
                              hipStream_t stream) {
  const int B = 8, S = 2048, D = 768;

  const float* Zg  = (const float*)d_in[0];
  const float* Zl  = (const float*)d_in[1];
  const float* bqg = (const float*)d_in[3];
  const float* bkl = (const float*)d_in[5];
  const float* bvl = (const float*)d_in[7];
  const float* bql = (const float*)d_in[9];
  const float* bkg = (const float*)d_in[11];
  const float* bvg = (const float*)d_in[13];
  const float* bf  = (const float*)d_in[15];

  // Footprint: weights + 6 group buffers + [split-K f32 accum] +
  //            max(Zbf pair, score chunk) + 1MB margin.
  // need(2,sk)=93.2MB <= 98MB <= known ws lower bound -> sk engages at G=2.
  auto need = [&](int G, bool sk) -> size_t {
    size_t zrow = (size_t)G * S * D * 2;
    size_t sb = (size_t)2 * G * S * S * 2;
    size_t zacc = sk ? (size_t)G * S * D * 4 : 0;
    size_t zbf = 2 * zrow;
    return 7 * ((size_t)D * D * 2) + 6 * zrow + zacc + (sb > zbf ? sb : zbf) + (1u << 20);
  };
  int G; bool SK;
  if      (ws_size >= need(8, true)) { G = 8; SK = true; }
  else if (ws_size >= need(4, true)) { G = 4; SK = true; }
  else if (ws_size >= need(2, true)) { G = 2; SK = true; }
  else if (ws_size >= need(1, true)) { G = 1; SK = true; }
  else                               { G = 1; SK = false; }
  const int SG = G * S;

  char* w = (char*)d_ws;
  size_t off = 0;
  auto alloc = [&](size_t bytes) -> char* {
    char* p = w + off; off += (bytes + 255) & ~(size_t)255; return p;
  };
  const size_t ZROW = (size_t)SG * D * 2;
  unsigned short* Wbf[7];
  for (int i = 0; i < 7; ++i) Wbf[i] = (unsigned short*)alloc((size_t)D * D * 2);
  unsigned short* QgZf  = (unsigned short*)alloc(ZROW);  // Qg, then reused as Zf
  unsigned short* Kl    = (unsigned short*)alloc(ZROW);
  unsigned short* Ql    = (unsigned short*)alloc(ZROW);
  unsigned short* Kg    = (unsigned short*)alloc(ZROW);
  unsigned short* VlT   = (unsigned short*)alloc(ZROW);  // [768][SG]
  unsigned short* VgT   = (unsigned short*)alloc(ZROW);  // [768][SG]
  float* Zacc = SK ? (float*)alloc((size_t)SG * D * 4) : nullptr;
  // Overlay: Zg_bf/Zl_bf (convert->projvt) share space with Sb (scores->pv)
  size_t ov = off;
  unsigned short* Zg_bf = (unsigned short*)alloc(ZROW);
  unsigned short* Zl_bf = (unsigned short*)alloc(ZROW);
  unsigned short* Sb    = (unsigned short*)(w + ov);

  // weights fp32 -> bf16 (once). Order: Wqg Wkl Wvl Wql Wkg Wvg Wf.
  ConvW cw;
  cw.src[0] = (const float*)d_in[2];  cw.src[1] = (const float*)d_in[4];
  cw.src[2] = (const float*)d_in[6];  cw.src[3] = (const float*)d_in[8];
  cw.src[4] = (const float*)d_in[10]; cw.src[5] = (const float*)d_in[12];
  cw.src[6] = (const float*)d_in[14];
  for (int i = 0; i < 7; ++i) cw.dst[i] = Wbf[i];
  k_convert_w<<<dim3(576, 7), NT, 0, stream>>>(cw);

  ProjArgs pa;
  pa.src[0] = Zg_bf; pa.W[0] = Wbf[0]; pa.bias[0] = bqg; pa.dst[0] = QgZf;
  pa.src[1] = Zl_bf; pa.W[1] = Wbf[1]; pa.bias[1] = bkl; pa.dst[1] = Kl;
  pa.src[2] = Zl_bf; pa.W[2] = Wbf[3]; pa.bias[2] = bql; pa.dst[2] = Ql;
  pa.src[3] = Zg_bf; pa.W[3] = Wbf[4]; pa.bias[3] = bkg; pa.dst[3] = Kg;
  ProjVTArgs pv;
  pv.Wv[0] = Wbf[2]; pv.Z[0] = Zl_bf; pv.bias[0] = bvl; pv.dst[0] = VlT;
  pv.Wv[1] = Wbf[5]; pv.Z[1] = Zg_bf; pv.bias[1] = bvg; pv.dst[1] = VgT;
  pv.ldc = SG;

  float alpha = 1.0f / sqrtf(768.0f);
  const int nZ = SG * D;  // group elements (multiple of 1024)

  for (int b0 = 0; b0 < B; b0 += G) {
    k_convert_z<<<dim3(1024, 2), NT, 0, stream>>>(Zg, Zl, Zg_bf, Zl_bf,
                                                  (long long)b0 * S * D, nZ);
    k_proj<<<dim3(6, SG / TILE, 4), NT, 0, stream>>>(pa);
    k_projvt<<<dim3(SG / TILE, 6, 2), NT, 0, stream>>>(pv);
    k_scores<<<dim3(16, 16, 2 * G), NT, 0, stream>>>(QgZf, Kl, Ql, Kg, Sb, alpha, G);
    k_softmax<<<dim3(2 * G * S), NT, 0, stream>>>(Sb);
    if (SK) {
      k_zero<<<dim3(nZ / (NT * 4)), NT, 0, stream>>>(Zacc, nZ / 4);
      k_pv_sk<<<dim3(6, 16, 4 * G), NT, 0, stream>>>(Sb, VlT, VgT, Zacc, G, SG);
      k_zf<<<dim3(nZ / (NT * 4)), NT, 0, stream>>>(Zacc, QgZf, nZ);
    } else {
      k_pv<<<dim3(6, 16, G), NT, 0, stream>>>(Sb, VlT, VgT, QgZf, G, SG);
    }
    k_final<<<dim3(6, SG / TILE), NT, 0, stream>>>(QgZf, Wbf[6], bf,
                                                   (float*)d_out + (size_t)b0 * S * D);
  }
}

// Round 8
// 703.465 us; speedup vs baseline: 1.1228x; 1.1228x over previous
//
#include <hip/hip_runtime.h>
#include <math.h>

#define TILE 128
#define BK   64
#define NT   256

typedef __attribute__((ext_vector_type(8))) short bf16x8;
typedef __attribute__((ext_vector_type(4))) float f32x4;

typedef const __attribute__((address_space(1))) void* gvp;
typedef __attribute__((address_space(3))) void* lvp;

__device__ __forceinline__ float bf2f(unsigned short u) {
  union { unsigned int i; float f; } v; v.i = ((unsigned int)u) << 16; return v.f;
}
__device__ __forceinline__ unsigned short f2bf(float f) {
  union { float ff; unsigned int i; } v; v.ff = f;
  return (unsigned short)((v.i + 0x7fffu + ((v.i >> 16) & 1u)) >> 16);
}

// bijective XCD-chunk swizzle (m204): dispatch round-robins linear ids across
// 8 XCDs; remap so each XCD owns a contiguous logical chunk -> blocks sharing
// an input panel hit the same XCD L2. (R7 measured: FETCH 260->55MB on PV.)
__device__ __forceinline__ int xcd_swz(int h, int nwg) {
  int q = nwg >> 3, r = nwg & 7;
  int xcd = h & 7, pos = h >> 3;
  return (xcd < r ? xcd * (q + 1) : r * (q + 1) + (xcd - r) * q) + pos;
}

struct GemmSrc { const unsigned short* A; int lda; const unsigned short* B; int ldb; int nk; };

// Stage a 128x64 bf16 tile into LDS: 1024 16B chunks, 4 per thread.
// Exactly 4 global_load_lds (VMEM ops) per thread per call.
__device__ __forceinline__ void stage_tile(const unsigned short* g, int ld, int r0, int k0,
                                           short* lds, int tid) {
#pragma unroll
  for (int i = 0; i < 4; ++i) {
    int cid = i * NT + tid;
    int row = cid >> 3, kc = cid & 7;
    const unsigned short* src = g + (size_t)(r0 + row) * ld + (k0 + kc * 8);
    __builtin_amdgcn_global_load_lds((gvp)src, (lvp)(lds + cid * 8), 16, 0, 0);
  }
}

__device__ __forceinline__ void compute_tile(const short* As, const short* Bs,
                                             f32x4 acc[4][4], int lr, int lk, int wm, int wn) {
#pragma unroll
  for (int kk = 0; kk < 2; ++kk) {
    bf16x8 a[4], b[4];
#pragma unroll
    for (int i = 0; i < 4; ++i) {
      a[i] = *(const bf16x8*)(As + (wm * 64 + i * 16 + lr) * BK + kk * 32 + lk * 8);
      b[i] = *(const bf16x8*)(Bs + (wn * 64 + i * 16 + lr) * BK + kk * 32 + lk * 8);
    }
#pragma unroll
    for (int i = 0; i < 4; ++i)
#pragma unroll
      for (int j = 0; j < 4; ++j)
        acc[i][j] = __builtin_amdgcn_mfma_f32_16x16x32_bf16(a[i], b[j], acc[i][j], 0, 0, 0);
  }
}

// single-buffered K-loop (for kernels with >=2-4 blocks/CU: inter-wave overlap)
template<int NS>
__device__ __forceinline__ void gemm_accum(const GemmSrc* s, f32x4 acc[4][4],
                                           short* As, short* Bs, int tid, int r0, int c0) {
  int lane = tid & 63, w = tid >> 6;
  int lr = lane & 15, lk = lane >> 4;
  int wm = w >> 1, wn = w & 1;
#pragma unroll
  for (int si = 0; si < NS; ++si) {
    int nk = s[si].nk;
    for (int kt = 0; kt < nk; ++kt) {
      __syncthreads();
      stage_tile(s[si].A, s[si].lda, r0, kt * BK, As, tid);
      stage_tile(s[si].B, s[si].ldb, c0, kt * BK, Bs, tid);
      __syncthreads();
      compute_tile(As, Bs, acc, lr, lk, wm, wn);
    }
  }
}

// map flat K-step -> (source, local kt) and stage its A/B tiles (8 VMEM ops)
template<int NS>
__device__ __forceinline__ void stage_step(const GemmSrc* s, int step, short* A, short* B,
                                           int r0, int c0, int tid) {
  int si = 0, t = step;
#pragma unroll
  for (int i = 0; i < NS - 1; ++i) { if (t >= s[i].nk) { t -= s[i].nk; si = i + 1; } }
  stage_tile(s[si].A, s[si].lda, r0, t * BK, A, tid);
  stage_tile(s[si].B, s[si].ldb, c0, t * BK, B, tid);
}

// T4 counted-vmcnt double-buffered K-loop, for the 1-block/CU regime where no
// other wave hides the drain. Per iter: barrier(a) [prev readers done before
// next-writer issue] -> issue stage(t+1) -> s_waitcnt vmcnt(8) [tile t's own 8
// loads done; t+1's 8 stay in flight ACROSS the barrier] -> raw s_barrier(b)
// [all waves' t-loads landed] -> compute(t). ds_reads cannot hoist above the
// "memory"-clobbered waitcnt asm; raw s_barrier has no implicit vmcnt(0) drain.
template<int NS>
__device__ __forceinline__ void gemm_accum_pipe(const GemmSrc* s, f32x4 acc[4][4],
                                                short* As0, short* Bs0, short* As1, short* Bs1,
                                                int tid, int r0, int c0) {
  int lane = tid & 63, w = tid >> 6;
  int lr = lane & 15, lk = lane >> 4;
  int wm = w >> 1, wn = w & 1;
  int total = 0;
#pragma unroll
  for (int si = 0; si < NS; ++si) total += s[si].nk;
  stage_step<NS>(s, 0, As0, Bs0, r0, c0, tid);         // 8 loads in flight
  for (int t = 0; t < total; ++t) {
    short* Ac = (t & 1) ? As1 : As0;
    short* Bc = (t & 1) ? Bs1 : Bs0;
    short* An = (t & 1) ? As0 : As1;
    short* Bn = (t & 1) ? Bs0 : Bs1;
    __builtin_amdgcn_s_barrier();                      // (a) compute(t-1) done everywhere
    asm volatile("" ::: "memory");
    if (t + 1 < total) {
      stage_step<NS>(s, t + 1, An, Bn, r0, c0, tid);   // +8 -> 16 outstanding
      asm volatile("s_waitcnt vmcnt(8)" ::: "memory"); // tile t's 8 complete
    } else {
      asm volatile("s_waitcnt vmcnt(0)" ::: "memory"); // last tile: full drain
    }
    __builtin_amdgcn_s_barrier();                      // (b) all waves' t-loads landed
    asm volatile("" ::: "memory");
    compute_tile(Ac, Bc, acc, lr, lk, wm, wn);
  }
}

// C/D layout for mfma_f32_16x16x32_bf16: col = lane&15, row = (lane>>4)*4 + reg
template<bool OUT_BF16, bool BIAS_N, bool BIAS_M>
__device__ __forceinline__ void gemm_epilogue(f32x4 acc[4][4], void* C, int ldc,
                                              int r0, int c0, const float* bias,
                                              float alpha, int tid) {
  int lane = tid & 63, w = tid >> 6;
  int lr = lane & 15, lk = lane >> 4;
  int wm = w >> 1, wn = w & 1;
#pragma unroll
  for (int i = 0; i < 4; ++i) {
#pragma unroll
    for (int j = 0; j < 4; ++j) {
      int col = c0 + wn * 64 + j * 16 + lr;
      float bn = BIAS_N ? bias[col] : 0.f;
#pragma unroll
      for (int r = 0; r < 4; ++r) {
        int row = r0 + wm * 64 + i * 16 + lk * 4 + r;
        float v = acc[i][j][r] * alpha + bn;
        if (BIAS_M) v += bias[row];
        size_t idx = (size_t)row * ldc + col;
        if (OUT_BF16) ((unsigned short*)C)[idx] = f2bf(v);
        else          ((float*)C)[idx] = v;
      }
    }
  }
}

__device__ __forceinline__ void zero_acc(f32x4 acc[4][4]) {
  f32x4 z = { 0.f, 0.f, 0.f, 0.f };
#pragma unroll
  for (int i = 0; i < 4; ++i)
#pragma unroll
    for (int j = 0; j < 4; ++j) acc[i][j] = z;
}

// ---------------- kernels ----------------

struct ConvW { const float* src[7]; unsigned short* dst[7]; };

__global__ __launch_bounds__(NT) void k_convert_w(ConvW a) {
  int z = blockIdx.y;
  const float* s = a.src[z];
  unsigned short* d = a.dst[z];
  const int n = 768 * 768;
  int stride = gridDim.x * NT * 4;
  for (int i = ((int)blockIdx.x * NT + (int)threadIdx.x) * 4; i < n; i += stride) {
    float4 f = *(const float4*)(s + i);
    ushort4 o;
    o.x = f2bf(f.x); o.y = f2bf(f.y); o.z = f2bf(f.z); o.w = f2bf(f.w);
    *(ushort4*)(d + i) = o;
  }
}

__global__ __launch_bounds__(NT) void k_convert_z(const float* zg, const float* zl,
                                                  unsigned short* dg, unsigned short* dl,
                                                  long long off, int n) {
  const float* s = (blockIdx.y ? zl : zg) + off;
  unsigned short* d = blockIdx.y ? dl : dg;
  int stride = gridDim.x * NT * 4;
  for (int i = ((int)blockIdx.x * NT + (int)threadIdx.x) * 4; i < n; i += stride) {
    float4 f = *(const float4*)(s + i);
    ushort4 o;
    o.x = f2bf(f.x); o.y = f2bf(f.y); o.z = f2bf(f.z); o.w = f2bf(f.w);
    *(ushort4*)(d + i) = o;
  }
}

struct ProjArgs {
  const unsigned short* src[4];
  const unsigned short* W[4];
  const float* bias[4];
  unsigned short* dst[4];
};

// dst = src @ W^T + b : M=SG, N=768, K=768 (group-local rows)
__global__ __launch_bounds__(NT) void k_proj(ProjArgs p) {
  __shared__ __align__(16) short As[TILE * BK], Bs[TILE * BK];
  int z = blockIdx.z;
  int r0 = blockIdx.y * TILE, c0 = blockIdx.x * TILE;
  f32x4 acc[4][4]; zero_acc(acc);
  GemmSrc s = { p.src[z], 768, p.W[z], 768, 768 / BK };
  gemm_accum<1>(&s, acc, As, Bs, threadIdx.x, r0, c0);
  gemm_epilogue<true, true, false>(acc, p.dst[z], 768, r0, c0, p.bias[z], 1.f, threadIdx.x);
}

struct ProjVTArgs {
  const unsigned short* Wv[2];
  const unsigned short* Z[2];
  const float* bias[2];
  unsigned short* dst[2];
  int ldc;  // = SG
};

// V^T = Wv @ Z_grp^T (+ bias per ROW e) : M=768, N=SG, K=768, C is [768][SG]
__global__ __launch_bounds__(NT) void k_projvt(ProjVTArgs p) {
  __shared__ __align__(16) short As[TILE * BK], Bs[TILE * BK];
  int z = blockIdx.z;
  int r0 = blockIdx.y * TILE, c0 = blockIdx.x * TILE;
  f32x4 acc[4][4]; zero_acc(acc);
  GemmSrc s = { p.Wv[z], 768, p.Z[z], 768, 768 / BK };
  gemm_accum<1>(&s, acc, As, Bs, threadIdx.x, r0, c0);
  gemm_epilogue<true, false, true>(acc, p.dst[z], p.ldc, r0, c0, p.bias[z], 1.f, threadIdx.x);
}

// S[z] = Q_gi @ K_gi^T * alpha, group-local: z in [0,2G). XCD-swizzled.
__global__ __launch_bounds__(NT) void k_scores(const unsigned short* Qg, const unsigned short* Kl,
                                               const unsigned short* Ql, const unsigned short* Kg,
                                               unsigned short* S, float alpha, int G) {
  __shared__ __align__(16) short As[TILE * BK], Bs[TILE * BK];
  int nwg = (int)(gridDim.x * gridDim.y * gridDim.z);
  int h = (int)blockIdx.x + (int)gridDim.x * ((int)blockIdx.y + (int)gridDim.y * (int)blockIdx.z);
  int l = xcd_swz(h, nwg);
  int x = l & 15, y = (l >> 4) & 15, z = l >> 8;
  int dir = (z >= G) ? 1 : 0, gi = z - dir * G;
  const unsigned short* Q = (dir ? Ql : Qg) + (size_t)gi * 2048 * 768;
  const unsigned short* K = (dir ? Kg : Kl) + (size_t)gi * 2048 * 768;
  unsigned short* C = S + (size_t)z * 2048 * 2048;
  int r0 = y * TILE, c0 = x * TILE;
  f32x4 acc[4][4]; zero_acc(acc);
  GemmSrc s = { Q, 768, K, 768, 768 / BK };
  gemm_accum<1>(&s, acc, As, Bs, threadIdx.x, r0, c0);
  gemm_epilogue<true, false, false>(acc, C, 2048, r0, c0, nullptr, alpha, threadIdx.x);
}

// in-place row softmax over 2048 bf16, one block per row
__global__ __launch_bounds__(NT) void k_softmax(unsigned short* S) {
  __shared__ float red[8];
  unsigned short* p = S + (size_t)blockIdx.x * 2048;
  int t = threadIdx.x, lane = t & 63, w = t >> 6;
  union { uint4 q; unsigned short u[8]; } raw;
  raw.q = ((const uint4*)p)[t];
  float v[8]; float mx = -3.0e38f;
#pragma unroll
  for (int i = 0; i < 8; ++i) { v[i] = bf2f(raw.u[i]); mx = fmaxf(mx, v[i]); }
#pragma unroll
  for (int off = 32; off > 0; off >>= 1) mx = fmaxf(mx, __shfl_xor(mx, off));
  if (lane == 0) red[w] = mx;
  __syncthreads();
  mx = fmaxf(fmaxf(red[0], red[1]), fmaxf(red[2], red[3]));
  float sum = 0.f;
#pragma unroll
  for (int i = 0; i < 8; ++i) { v[i] = __expf(v[i] - mx); sum += v[i]; }
#pragma unroll
  for (int off = 32; off > 0; off >>= 1) sum += __shfl_xor(sum, off);
  if (lane == 0) red[4 + w] = sum;
  __syncthreads();
  sum = (red[4] + red[5]) + (red[6] + red[7]);
  float inv = 1.f / sum;
#pragma unroll
  for (int i = 0; i < 8; ++i) raw.u[i] = f2bf(v[i] * inv);
  ((uint4*)p)[t] = raw.q;
}

// Zf[gi] = P_g2l @ Vl + P_l2g @ Vg, M=2048, N=768, K=2048 per source
// (accumulated in one acc). Counted-vmcnt dbuf pipeline + XCD swizzle:
// grid 6*16*G is ~1 block/CU, so intra-block prefetch is the only overlap.
__global__ __launch_bounds__(NT) void k_pv(const unsigned short* S, const unsigned short* VlT,
                                           const unsigned short* VgT, unsigned short* Zf,
                                           int G, int SG) {
  __shared__ __align__(16) short As0[TILE * BK], Bs0[TILE * BK];
  __shared__ __align__(16) short As1[TILE * BK], Bs1[TILE * BK];
  int nwg = (int)(gridDim.x * gridDim.y * gridDim.z);
  int h = (int)blockIdx.x + (int)gridDim.x * ((int)blockIdx.y + (int)gridDim.y * (int)blockIdx.z);
  int l = xcd_swz(h, nwg);
  int x = l % 6, t2 = l / 6;
  int y = t2 & 15, z = t2 >> 4;        // z in [0,G)
  int r0 = y * TILE, c0 = x * TILE;
  f32x4 acc[4][4]; zero_acc(acc);
  GemmSrc s[2] = {
    { S + (size_t)z * 2048 * 2048,       2048, VlT + (size_t)z * 2048, SG, 2048 / BK },
    { S + (size_t)(G + z) * 2048 * 2048, 2048, VgT + (size_t)z * 2048, SG, 2048 / BK }
  };
  gemm_accum_pipe<2>(s, acc, As0, Bs0, As1, Bs1, threadIdx.x, r0, c0);
  gemm_epilogue<true, false, false>(acc, Zf + (size_t)z * 2048 * 768, 768, r0, c0,
                                    nullptr, 1.f, threadIdx.x);
}

// out_grp = Zf_grp @ Wf^T + bf (fp32 out) : M=SG, N=768, K=768
__global__ __launch_bounds__(NT) void k_final(const unsigned short* Zf, const unsigned short* Wf,
                                              const float* bias, float* out) {
  __shared__ __align__(16) short As[TILE * BK], Bs[TILE * BK];
  int r0 = blockIdx.y * TILE, c0 = blockIdx.x * TILE;
  f32x4 acc[4][4]; zero_acc(acc);
  GemmSrc s = { Zf, 768, Wf, 768, 768 / BK };
  gemm_accum<1>(&s, acc, As, Bs, threadIdx.x, r0, c0);
  gemm_epilogue<false, true, false>(acc, out, 768, r0, c0, bias, 1.f, threadIdx.x);
}

// ---------------- launch ----------------

extern "C" void kernel_launch(void* const* d_in, const int* in_sizes, int n_in,
                              void* d_out, int out_size, void* d_ws, size_t ws_size,
                              hipStream_t stream) {
  const int B = 8, S = 2048, D = 768;

  const float* Zg  = (const float*)d_in[0];
  const float* Zl  = (const float*)d_in[1];
  const float* bqg = (const float*)d_in[3];
  const float* bkl = (const float*)d_in[5];
  const float* bvl = (const float*)d_in[7];
  const float* bql = (const float*)d_in[9];
  const float* bkg = (const float*)d_in[11];
  const float* bvg = (const float*)d_in[13];
  const float* bf  = (const float*)d_in[15];

  // need(G) = 7 weights + 6 group buffers + max(Zbf pair, 2G score slices) + 1MB
  // G=8: 294.5MB, G=4: 151.9MB, G=2: 80.6MB, G=1: 44.9MB.
  // Known from R5-R7 runs: ws in [93.2, 150.9) MB -> G=2 engages.
  auto needG = [&](int G) -> size_t {
    size_t zrow = (size_t)G * S * D * 2;
    size_t sb = (size_t)2 * G * S * S * 2;
    size_t zbf = 2 * zrow;
    return 7 * ((size_t)D * D * 2) + 6 * zrow + (sb > zbf ? sb : zbf) + (1u << 20);
  };
  int G = 1;
  if      (ws_size >= needG(8)) G = 8;
  else if (ws_size >= needG(4)) G = 4;
  else if (ws_size >= needG(2)) G = 2;
  const int SG = G * S;

  char* w = (char*)d_ws;
  size_t off = 0;
  auto alloc = [&](size_t bytes) -> char* {
    char* p = w + off; off += (bytes + 255) & ~(size_t)255; return p;
  };
  const size_t ZROW = (size_t)SG * D * 2;
  unsigned short* Wbf[7];
  for (int i = 0; i < 7; ++i) Wbf[i] = (unsigned short*)alloc((size_t)D * D * 2);
  unsigned short* QgZf  = (unsigned short*)alloc(ZROW);  // Qg, then reused as Zf
  unsigned short* Kl    = (unsigned short*)alloc(ZROW);
  unsigned short* Ql    = (unsigned short*)alloc(ZROW);
  unsigned short* Kg    = (unsigned short*)alloc(ZROW);
  unsigned short* VlT   = (unsigned short*)alloc(ZROW);  // [768][SG]
  unsigned short* VgT   = (unsigned short*)alloc(ZROW);  // [768][SG]
  // Overlay: Zg_bf/Zl_bf (convert->projvt) share space with Sb (scores->pv)
  size_t ov = off;
  unsigned short* Zg_bf = (unsigned short*)alloc(ZROW);
  unsigned short* Zl_bf = (unsigned short*)alloc(ZROW);
  unsigned short* Sb    = (unsigned short*)(w + ov);

  // weights fp32 -> bf16 (once). Order: Wqg Wkl Wvl Wql Wkg Wvg Wf.
  ConvW cw;
  cw.src[0] = (const float*)d_in[2];  cw.src[1] = (const float*)d_in[4];
  cw.src[2] = (const float*)d_in[6];  cw.src[3] = (const float*)d_in[8];
  cw.src[4] = (const float*)d_in[10]; cw.src[5] = (const float*)d_in[12];
  cw.src[6] = (const float*)d_in[14];
  for (int i = 0; i < 7; ++i) cw.dst[i] = Wbf[i];
  k_convert_w<<<dim3(576, 7), NT, 0, stream>>>(cw);

  ProjArgs pa;
  pa.src[0] = Zg_bf; pa.W[0] = Wbf[0]; pa.bias[0] = bqg; pa.dst[0] = QgZf;
  pa.src[1] = Zl_bf; pa.W[1] = Wbf[1]; pa.bias[1] = bkl; pa.dst[1] = Kl;
  pa.src[2] = Zl_bf; pa.W[2] = Wbf[3]; pa.bias[2] = bql; pa.dst[2] = Ql;
  pa.src[3] = Zg_bf; pa.W[3] = Wbf[4]; pa.bias[3] = bkg; pa.dst[3] = Kg;
  ProjVTArgs pv;
  pv.Wv[0] = Wbf[2]; pv.Z[0] = Zl_bf; pv.bias[0] = bvl; pv.dst[0] = VlT;
  pv.Wv[1] = Wbf[5]; pv.Z[1] = Zg_bf; pv.bias[1] = bvg; pv.dst[1] = VgT;
  pv.ldc = SG;

  float alpha = 1.0f / sqrtf(768.0f);
  const int nZ = SG * D;

  for (int b0 = 0; b0 < B; b0 += G) {
    k_convert_z<<<dim3(1024, 2), NT, 0, stream>>>(Zg, Zl, Zg_bf, Zl_bf,
                                                  (long long)b0 * S * D, nZ);
    k_proj<<<dim3(6, SG / TILE, 4), NT, 0, stream>>>(pa);
    k_projvt<<<dim3(SG / TILE, 6, 2), NT, 0, stream>>>(pv);
    k_scores<<<dim3(16, 16, 2 * G), NT, 0, stream>>>(QgZf, Kl, Ql, Kg, Sb, alpha, G);
    k_softmax<<<dim3(2 * G * S), NT, 0, stream>>>(Sb);
    k_pv<<<dim3(6, 16, G), NT, 0, stream>>>(Sb, VlT, VgT, QgZf, G, SG);
    k_final<<<dim3(6, SG / TILE), NT, 0, stream>>>(QgZf, Wbf[6], bf,
                                                   (float*)d_out + (size_t)b0 * S * D);
  }
}

// Round 9
// 580.831 us; speedup vs baseline: 1.3598x; 1.2111x over previous
//
#include <hip/hip_runtime.h>
#include <math.h>

#define TILE 128
#define BK   64
#define NT   256

typedef __attribute__((ext_vector_type(8))) short bf16x8;
typedef __attribute__((ext_vector_type(4))) float f32x4;

typedef const __attribute__((address_space(1))) void* gvp;
typedef __attribute__((address_space(3))) void* lvp;

__device__ __forceinline__ float bf2f(unsigned short u) {
  union { unsigned int i; float f; } v; v.i = ((unsigned int)u) << 16; return v.f;
}
__device__ __forceinline__ unsigned short f2bf(float f) {
  union { float ff; unsigned int i; } v; v.ff = f;
  return (unsigned short)((v.i + 0x7fffu + ((v.i >> 16) & 1u)) >> 16);
}

// bijective XCD-chunk swizzle (m204). R7/R8 measured: PV FETCH 260->55MB.
__device__ __forceinline__ int xcd_swz(int h, int nwg) {
  int q = nwg >> 3, r = nwg & 7;
  int xcd = h & 7, pos = h >> 3;
  return (xcd < r ? xcd * (q + 1) : r * (q + 1) + (xcd - r) * q) + pos;
}

struct GemmSrc { const unsigned short* A; int lda; const unsigned short* B; int ldb; int nk; };

// Stage a 128x64 bf16 tile into LDS. T2 bank-conflict swizzle, rule #21 form:
// LDS dest stays LINEAR (global_load_lds requirement); the SOURCE k-chunk is
// inverse-swizzled, so LDS slot (row, kc) holds global chunk kc^(row&7).
// 4 global_load_lds (VMEM ops) per thread per call.
__device__ __forceinline__ void stage_tile(const unsigned short* g, int ld, int r0, int k0,
                                           short* lds, int tid) {
#pragma unroll
  for (int i = 0; i < 4; ++i) {
    int cid = i * NT + tid;
    int row = cid >> 3, kc = cid & 7;
    int kcs = kc ^ (row & 7);                          // T2 source swizzle (involution)
    const unsigned short* src = g + (size_t)(r0 + row) * ld + (k0 + kcs * 8);
    __builtin_amdgcn_global_load_lds((gvp)src, (lvp)(lds + cid * 8), 16, 0, 0);
  }
}

// Fragment reads apply the matching XOR: chunk (kk*4+lk) of row r lives at
// LDS chunk (kk*4+lk)^(r&7). Lanes lr=0..15 then spread over 8 bank-quads
// (4-way residual, ~free per m136) instead of one (16-way, ~5.7x).
__device__ __forceinline__ void compute_tile(const short* As, const short* Bs,
                                             f32x4 acc[4][4], int lr, int lk, int wm, int wn) {
#pragma unroll
  for (int kk = 0; kk < 2; ++kk) {
    bf16x8 a[4], b[4];
#pragma unroll
    for (int i = 0; i < 4; ++i) {
      int ra = wm * 64 + i * 16 + lr;
      int rb = wn * 64 + i * 16 + lr;
      int ca = ((kk * 4 + lk) ^ (ra & 7)) * 8;
      int cb = ((kk * 4 + lk) ^ (rb & 7)) * 8;
      a[i] = *(const bf16x8*)(As + ra * BK + ca);
      b[i] = *(const bf16x8*)(Bs + rb * BK + cb);
    }
#pragma unroll
    for (int i = 0; i < 4; ++i)
#pragma unroll
      for (int j = 0; j < 4; ++j)
        acc[i][j] = __builtin_amdgcn_mfma_f32_16x16x32_bf16(a[i], b[j], acc[i][j], 0, 0, 0);
  }
}

// single-buffered K-loop (kernels with >=2-4 blocks/CU: inter-wave overlap)
template<int NS>
__device__ __forceinline__ void gemm_accum(const GemmSrc* s, f32x4 acc[4][4],
                                           short* As, short* Bs, int tid, int r0, int c0) {
  int lane = tid & 63, w = tid >> 6;
  int lr = lane & 15, lk = lane >> 4;
  int wm = w >> 1, wn = w & 1;
#pragma unroll
  for (int si = 0; si < NS; ++si) {
    int nk = s[si].nk;
    for (int kt = 0; kt < nk; ++kt) {
      __syncthreads();
      stage_tile(s[si].A, s[si].lda, r0, kt * BK, As, tid);
      stage_tile(s[si].B, s[si].ldb, c0, kt * BK, Bs, tid);
      __syncthreads();
      compute_tile(As, Bs, acc, lr, lk, wm, wn);
    }
  }
}

// map flat K-step -> (source, local kt) and stage its A/B tiles
template<int NS>
__device__ __forceinline__ void stage_step(const GemmSrc* s, int step, short* A, short* B,
                                           int r0, int c0, int tid) {
  int si = 0, t = step;
#pragma unroll
  for (int i = 0; i < NS - 1; ++i) { if (t >= s[i].nk) { t -= s[i].nk; si = i + 1; } }
  stage_tile(s[si].A, s[si].lda, r0, t * BK, A, tid);
  stage_tile(s[si].B, s[si].ldb, c0, t * BK, B, tid);
}

// double-buffered K-loop (R6-measured best for the 1-block/CU k_pv regime;
// R8's counted-vmcnt variant measured -15%, reverted).
template<int NS>
__device__ __forceinline__ void gemm_accum_dbuf(const GemmSrc* s, f32x4 acc[4][4],
                                                short* As0, short* Bs0, short* As1, short* Bs1,
                                                int tid, int r0, int c0) {
  int lane = tid & 63, w = tid >> 6;
  int lr = lane & 15, lk = lane >> 4;
  int wm = w >> 1, wn = w & 1;
  int total = 0;
#pragma unroll
  for (int si = 0; si < NS; ++si) total += s[si].nk;
  stage_step<NS>(s, 0, As0, Bs0, r0, c0, tid);
  __syncthreads();
  for (int step = 0; step < total; ++step) {
    short* Ac = (step & 1) ? As1 : As0;
    short* Bc = (step & 1) ? Bs1 : Bs0;
    short* An = (step & 1) ? As0 : As1;
    short* Bn = (step & 1) ? Bs0 : Bs1;
    if (step + 1 < total) stage_step<NS>(s, step + 1, An, Bn, r0, c0, tid);
    compute_tile(Ac, Bc, acc, lr, lk, wm, wn);
    __syncthreads();
  }
}

// C/D layout for mfma_f32_16x16x32_bf16: col = lane&15, row = (lane>>4)*4 + reg
template<bool OUT_BF16, bool BIAS_N, bool BIAS_M>
__device__ __forceinline__ void gemm_epilogue(f32x4 acc[4][4], void* C, int ldc,
                                              int r0, int c0, const float* bias,
                                              float alpha, int tid) {
  int lane = tid & 63, w = tid >> 6;
  int lr = lane & 15, lk = lane >> 4;
  int wm = w >> 1, wn = w & 1;
#pragma unroll
  for (int i = 0; i < 4; ++i) {
#pragma unroll
    for (int j = 0; j < 4; ++j) {
      int col = c0 + wn * 64 + j * 16 + lr;
      float bn = BIAS_N ? bias[col] : 0.f;
#pragma unroll
      for (int r = 0; r < 4; ++r) {
        int row = r0 + wm * 64 + i * 16 + lk * 4 + r;
        float v = acc[i][j][r] * alpha + bn;
        if (BIAS_M) v += bias[row];
        size_t idx = (size_t)row * ldc + col;
        if (OUT_BF16) ((unsigned short*)C)[idx] = f2bf(v);
        else          ((float*)C)[idx] = v;
      }
    }
  }
}

__device__ __forceinline__ void zero_acc(f32x4 acc[4][4]) {
  f32x4 z = { 0.f, 0.f, 0.f, 0.f };
#pragma unroll
  for (int i = 0; i < 4; ++i)
#pragma unroll
    for (int j = 0; j < 4; ++j) acc[i][j] = z;
}

// ---------------- kernels ----------------

struct ConvW { const float* src[7]; unsigned short* dst[7]; };

__global__ __launch_bounds__(NT) void k_convert_w(ConvW a) {
  int z = blockIdx.y;
  const float* s = a.src[z];
  unsigned short* d = a.dst[z];
  const int n = 768 * 768;
  int stride = gridDim.x * NT * 4;
  for (int i = ((int)blockIdx.x * NT + (int)threadIdx.x) * 4; i < n; i += stride) {
    float4 f = *(const float4*)(s + i);
    ushort4 o;
    o.x = f2bf(f.x); o.y = f2bf(f.y); o.z = f2bf(f.z); o.w = f2bf(f.w);
    *(ushort4*)(d + i) = o;
  }
}

__global__ __launch_bounds__(NT) void k_convert_z(const float* zg, const float* zl,
                                                  unsigned short* dg, unsigned short* dl,
                                                  long long off, int n) {
  const float* s = (blockIdx.y ? zl : zg) + off;
  unsigned short* d = blockIdx.y ? dl : dg;
  int stride = gridDim.x * NT * 4;
  for (int i = ((int)blockIdx.x * NT + (int)threadIdx.x) * 4; i < n; i += stride) {
    float4 f = *(const float4*)(s + i);
    ushort4 o;
    o.x = f2bf(f.x); o.y = f2bf(f.y); o.z = f2bf(f.z); o.w = f2bf(f.w);
    *(ushort4*)(d + i) = o;
  }
}

struct ProjArgs {
  const unsigned short* src[4];
  const unsigned short* W[4];
  const float* bias[4];
  unsigned short* dst[4];
};

// dst = src @ W^T + b : M=SG, N=768, K=768 (group-local rows)
__global__ __launch_bounds__(NT) void k_proj(ProjArgs p) {
  __shared__ __align__(16) short As[TILE * BK], Bs[TILE * BK];
  int z = blockIdx.z;
  int r0 = blockIdx.y * TILE, c0 = blockIdx.x * TILE;
  f32x4 acc[4][4]; zero_acc(acc);
  GemmSrc s = { p.src[z], 768, p.W[z], 768, 768 / BK };
  gemm_accum<1>(&s, acc, As, Bs, threadIdx.x, r0, c0);
  gemm_epilogue<true, true, false>(acc, p.dst[z], 768, r0, c0, p.bias[z], 1.f, threadIdx.x);
}

struct ProjVTArgs {
  const unsigned short* Wv[2];
  const unsigned short* Z[2];
  const float* bias[2];
  unsigned short* dst[2];
  int ldc;  // = SG
};

// V^T = Wv @ Z_grp^T (+ bias per ROW e) : M=768, N=SG, K=768, C is [768][SG]
__global__ __launch_bounds__(NT) void k_projvt(ProjVTArgs p) {
  __shared__ __align__(16) short As[TILE * BK], Bs[TILE * BK];
  int z = blockIdx.z;
  int r0 = blockIdx.y * TILE, c0 = blockIdx.x * TILE;
  f32x4 acc[4][4]; zero_acc(acc);
  GemmSrc s = { p.Wv[z], 768, p.Z[z], 768, 768 / BK };
  gemm_accum<1>(&s, acc, As, Bs, threadIdx.x, r0, c0);
  gemm_epilogue<true, false, true>(acc, p.dst[z], p.ldc, r0, c0, p.bias[z], 1.f, threadIdx.x);
}

// S[z] = Q_gi @ K_gi^T * alpha, group-local: z in [0,2G). XCD-swizzled.
__global__ __launch_bounds__(NT) void k_scores(const unsigned short* Qg, const unsigned short* Kl,
                                               const unsigned short* Ql, const unsigned short* Kg,
                                               unsigned short* S, float alpha, int G) {
  __shared__ __align__(16) short As[TILE * BK], Bs[TILE * BK];
  int nwg = (int)(gridDim.x * gridDim.y * gridDim.z);
  int h = (int)blockIdx.x + (int)gridDim.x * ((int)blockIdx.y + (int)gridDim.y * (int)blockIdx.z);
  int l = xcd_swz(h, nwg);
  int x = l & 15, y = (l >> 4) & 15, z = l >> 8;
  int dir = (z >= G) ? 1 : 0, gi = z - dir * G;
  const unsigned short* Q = (dir ? Ql : Qg) + (size_t)gi * 2048 * 768;
  const unsigned short* K = (dir ? Kg : Kl) + (size_t)gi * 2048 * 768;
  unsigned short* C = S + (size_t)z * 2048 * 2048;
  int r0 = y * TILE, c0 = x * TILE;
  f32x4 acc[4][4]; zero_acc(acc);
  GemmSrc s = { Q, 768, K, 768, 768 / BK };
  gemm_accum<1>(&s, acc, As, Bs, threadIdx.x, r0, c0);
  gemm_epilogue<true, false, false>(acc, C, 2048, r0, c0, nullptr, alpha, threadIdx.x);
}

// in-place row softmax over 2048 bf16, one block per row
__global__ __launch_bounds__(NT) void k_softmax(unsigned short* S) {
  __shared__ float red[8];
  unsigned short* p = S + (size_t)blockIdx.x * 2048;
  int t = threadIdx.x, lane = t & 63, w = t >> 6;
  union { uint4 q; unsigned short u[8]; } raw;
  raw.q = ((const uint4*)p)[t];
  float v[8]; float mx = -3.0e38f;
#pragma unroll
  for (int i = 0; i < 8; ++i) { v[i] = bf2f(raw.u[i]); mx = fmaxf(mx, v[i]); }
#pragma unroll
  for (int off = 32; off > 0; off >>= 1) mx = fmaxf(mx, __shfl_xor(mx, off));
  if (lane == 0) red[w] = mx;
  __syncthreads();
  mx = fmaxf(fmaxf(red[0], red[1]), fmaxf(red[2], red[3]));
  float sum = 0.f;
#pragma unroll
  for (int i = 0; i < 8; ++i) { v[i] = __expf(v[i] - mx); sum += v[i]; }
#pragma unroll
  for (int off = 32; off > 0; off >>= 1) sum += __shfl_xor(sum, off);
  if (lane == 0) red[4 + w] = sum;
  __syncthreads();
  sum = (red[4] + red[5]) + (red[6] + red[7]);
  float inv = 1.f / sum;
#pragma unroll
  for (int i = 0; i < 8; ++i) raw.u[i] = f2bf(v[i] * inv);
  ((uint4*)p)[t] = raw.q;
}

// Zf[gi] = P_g2l @ Vl + P_l2g @ Vg, M=2048, N=768, K=2048 per source
// (accumulated in one acc). dbuf (R6 best) + XCD swizzle (R7/R8 FETCH win).
__global__ __launch_bounds__(NT) void k_pv(const unsigned short* S, const unsigned short* VlT,
                                           const unsigned short* VgT, unsigned short* Zf,
                                           int G, int SG) {
  __shared__ __align__(16) short As0[TILE * BK], Bs0[TILE * BK];
  __shared__ __align__(16) short As1[TILE * BK], Bs1[TILE * BK];
  int nwg = (int)(gridDim.x * gridDim.y * gridDim.z);
  int h = (int)blockIdx.x + (int)gridDim.x * ((int)blockIdx.y + (int)gridDim.y * (int)blockIdx.z);
  int l = xcd_swz(h, nwg);
  int x = l % 6, t2 = l / 6;
  int y = t2 & 15, z = t2 >> 4;        // z in [0,G)
  int r0 = y * TILE, c0 = x * TILE;
  f32x4 acc[4][4]; zero_acc(acc);
  GemmSrc s[2] = {
    { S + (size_t)z * 2048 * 2048,       2048, VlT + (size_t)z * 2048, SG, 2048 / BK },
    { S + (size_t)(G + z) * 2048 * 2048, 2048, VgT + (size_t)z * 2048, SG, 2048 / BK }
  };
  gemm_accum_dbuf<2>(s, acc, As0, Bs0, As1, Bs1, threadIdx.x, r0, c0);
  gemm_epilogue<true, false, false>(acc, Zf + (size_t)z * 2048 * 768, 768, r0, c0,
                                    nullptr, 1.f, threadIdx.x);
}

// out_grp = Zf_grp @ Wf^T + bf (fp32 out) : M=SG, N=768, K=768
__global__ __launch_bounds__(NT) void k_final(const unsigned short* Zf, const unsigned short* Wf,
                                              const float* bias, float* out) {
  __shared__ __align__(16) short As[TILE * BK], Bs[TILE * BK];
  int r0 = blockIdx.y * TILE, c0 = blockIdx.x * TILE;
  f32x4 acc[4][4]; zero_acc(acc);
  GemmSrc s = { Zf, 768, Wf, 768, 768 / BK };
  gemm_accum<1>(&s, acc, As, Bs, threadIdx.x, r0, c0);
  gemm_epilogue<false, true, false>(acc, out, 768, r0, c0, bias, 1.f, threadIdx.x);
}

// ---------------- launch ----------------

extern "C" void kernel_launch(void* const* d_in, const int* in_sizes, int n_in,
                              void* d_out, int out_size, void* d_ws, size_t ws_size,
                              hipStream_t stream) {
  const int B = 8, S = 2048, D = 768;

  const float* Zg  = (const float*)d_in[0];
  const float* Zl  = (const float*)d_in[1];
  const float* bqg = (const float*)d_in[3];
  const float* bkl = (const float*)d_in[5];
  const float* bvl = (const float*)d_in[7];
  const float* bql = (const float*)d_in[9];
  const float* bkg = (const float*)d_in[11];
  const float* bvg = (const float*)d_in[13];
  const float* bf  = (const float*)d_in[15];

  // need(G) = 7 weights + 6 group buffers + max(Zbf pair, 2G score slices) + 1MB
  // G=8: 294.5MB, G=4: 151.9MB, G=2: 80.6MB. Known ws in [93.2, 150.9) -> G=2.
  auto needG = [&](int G) -> size_t {
    size_t zrow = (size_t)G * S * D * 2;
    size_t sb = (size_t)2 * G * S * S * 2;
    size_t zbf = 2 * zrow;
    return 7 * ((size_t)D * D * 2) + 6 * zrow + (sb > zbf ? sb : zbf) + (1u << 20);
  };
  int G = 1;
  if      (ws_size >= needG(8)) G = 8;
  else if (ws_size >= needG(4)) G = 4;
  else if (ws_size >= needG(2)) G = 2;
  const int SG = G * S;

  char* w = (char*)d_ws;
  size_t off = 0;
  auto alloc = [&](size_t bytes) -> char* {
    char* p = w + off; off += (bytes + 255) & ~(size_t)255; return p;
  };
  const size_t ZROW = (size_t)SG * D * 2;
  unsigned short* Wbf[7];
  for (int i = 0; i < 7; ++i) Wbf[i] = (unsigned short*)alloc((size_t)D * D * 2);
  unsigned short* QgZf  = (unsigned short*)alloc(ZROW);  // Qg, then reused as Zf
  unsigned short* Kl    = (unsigned short*)alloc(ZROW);
  unsigned short* Ql    = (unsigned short*)alloc(ZROW);
  unsigned short* Kg    = (unsigned short*)alloc(ZROW);
  unsigned short* VlT   = (unsigned short*)alloc(ZROW);  // [768][SG]
  unsigned short* VgT   = (unsigned short*)alloc(ZROW);  // [768][SG]
  // Overlay: Zg_bf/Zl_bf (convert->projvt) share space with Sb (scores->pv)
  size_t ov = off;
  unsigned short* Zg_bf = (unsigned short*)alloc(ZROW);
  unsigned short* Zl_bf = (unsigned short*)alloc(ZROW);
  unsigned short* Sb    = (unsigned short*)(w + ov);

  // weights fp32 -> bf16 (once). Order: Wqg Wkl Wvl Wql Wkg Wvg Wf.
  ConvW cw;
  cw.src[0] = (const float*)d_in[2];  cw.src[1] = (const float*)d_in[4];
  cw.src[2] = (const float*)d_in[6];  cw.src[3] = (const float*)d_in[8];
  cw.src[4] = (const float*)d_in[10]; cw.src[5] = (const float*)d_in[12];
  cw.src[6] = (const float*)d_in[14];
  for (int i = 0; i < 7; ++i) cw.dst[i] = Wbf[i];
  k_convert_w<<<dim3(576, 7), NT, 0, stream>>>(cw);

  ProjArgs pa;
  pa.src[0] = Zg_bf; pa.W[0] = Wbf[0]; pa.bias[0] = bqg; pa.dst[0] = QgZf;
  pa.src[1] = Zl_bf; pa.W[1] = Wbf[1]; pa.bias[1] = bkl; pa.dst[1] = Kl;
  pa.src[2] = Zl_bf; pa.W[2] = Wbf[3]; pa.bias[2] = bql; pa.dst[2] = Ql;
  pa.src[3] = Zg_bf; pa.W[3] = Wbf[4]; pa.bias[3] = bkg; pa.dst[3] = Kg;
  ProjVTArgs pv;
  pv.Wv[0] = Wbf[2]; pv.Z[0] = Zl_bf; pv.bias[0] = bvl; pv.dst[0] = VlT;
  pv.Wv[1] = Wbf[5]; pv.Z[1] = Zg_bf; pv.bias[1] = bvg; pv.dst[1] = VgT;
  pv.ldc = SG;

  float alpha = 1.0f / sqrtf(768.0f);
  const int nZ = SG * D;

  for (int b0 = 0; b0 < B; b0 += G) {
    k_convert_z<<<dim3(1024, 2), NT, 0, stream>>>(Zg, Zl, Zg_bf, Zl_bf,
                                                  (long long)b0 * S * D, nZ);
    k_proj<<<dim3(6, SG / TILE, 4), NT, 0, stream>>>(pa);
    k_projvt<<<dim3(SG / TILE, 6, 2), NT, 0, stream>>>(pv);
    k_scores<<<dim3(16, 16, 2 * G), NT, 0, stream>>>(QgZf, Kl, Ql, Kg, Sb, alpha, G);
    k_softmax<<<dim3(2 * G * S), NT, 0, stream>>>(Sb);
    k_pv<<<dim3(6, 16, G), NT, 0, stream>>>(Sb, VlT, VgT, QgZf, G, SG);
    k_final<<<dim3(6, SG / TILE), NT, 0, stream>>>(QgZf, Wbf[6], bf,
                                                   (float*)d_out + (size_t)b0 * S * D);
  }
}